// Round 1
// baseline (758.139 us; speedup 1.0000x reference)
//
#include <hip/hip_runtime.h>
#include <cstdint>

// Problem constants
#define B_SZ 4096
#define NN   30    // nodes
#define INC  512   // in channels
#define FF   128   // hidden
#define CC   9     // out channels

// ---------------------------------------------------------------------------
// Normalized adjacency: An[b] = D^-1/2 (A + I) D^-1/2 where A = (mean_bands != 0)
// ---------------------------------------------------------------------------
__global__ __launch_bounds__(128) void k_norm_adj(const float* __restrict__ graph,
                                                  float* __restrict__ An) {
  __shared__ float Ah[NN * NN];
  __shared__ float dinv[NN];
  const int b = blockIdx.x;
  const float* g = graph + (long)b * 5 * NN * NN;
  for (int e = threadIdx.x; e < NN * NN; e += 128) {
    float s = g[e] + g[e + 900] + g[e + 1800] + g[e + 2700] + g[e + 3600];
    float mean = s * 0.2f;
    int i = e / NN;
    int j = e - i * NN;
    Ah[e] = (mean != 0.0f || i == j) ? 1.0f : 0.0f;
  }
  __syncthreads();
  if (threadIdx.x < NN) {
    float d = 0.f;
#pragma unroll
    for (int j = 0; j < NN; ++j) d += Ah[threadIdx.x * NN + j];
    dinv[threadIdx.x] = (d > 0.f) ? (1.0f / sqrtf(d)) : 0.0f;
  }
  __syncthreads();
  float* ob = An + (long)b * NN * NN;
  for (int e = threadIdx.x; e < NN * NN; e += 128) {
    int i = e / NN;
    int j = e - i * NN;
    ob[e] = Ah[e] * dinv[i] * dinv[j];
  }
}

// ---------------------------------------------------------------------------
// fp32 GEMM: C[M x 128] = A[M x K] * B[K x 128], row-major. M % 128 == 0.
// BM=BN=128, BK=16, 256 threads, 8x8 outputs/thread.
// B-fragment columns are {4*tx..4*tx+3, 64+4*tx..64+4*tx+3} so the inner
// ds_read_b128s are <=2-way bank aliased (free on gfx950).
// ---------------------------------------------------------------------------
template <int K>
__global__ __launch_bounds__(256) void k_gemm(const float* __restrict__ A,
                                              const float* __restrict__ B,
                                              float* __restrict__ C) {
  constexpr int BM = 128, BN = 128, BK = 16;
  __shared__ float As[BK][BM + 4];  // stored transposed: As[k][m]
  __shared__ float Bs[BK][BN + 4];
  const int tid = threadIdx.x;
  const int tx = tid & 15;   // column group
  const int ty = tid >> 4;   // row group
  const long m0 = (long)blockIdx.x * BM;

  float acc[8][8];
#pragma unroll
  for (int i = 0; i < 8; ++i)
#pragma unroll
    for (int j = 0; j < 8; ++j) acc[i][j] = 0.f;

  for (int k0 = 0; k0 < K; k0 += BK) {
#pragma unroll
    for (int it = 0; it < 2; ++it) {
      int idx = tid + 256 * it;
      // A tile: 128 rows x 16 cols = 512 float4
      int arow = idx >> 2;
      int akq = idx & 3;
      float4 av = *(const float4*)(A + (m0 + arow) * (long)K + k0 + akq * 4);
      As[akq * 4 + 0][arow] = av.x;
      As[akq * 4 + 1][arow] = av.y;
      As[akq * 4 + 2][arow] = av.z;
      As[akq * 4 + 3][arow] = av.w;
      // B tile: 16 rows x 128 cols = 512 float4
      int brow = idx >> 5;
      int bc4 = idx & 31;
      float4 bv = *(const float4*)(B + (long)(k0 + brow) * BN + bc4 * 4);
      *(float4*)&Bs[brow][bc4 * 4] = bv;
    }
    __syncthreads();
#pragma unroll
    for (int k = 0; k < BK; ++k) {
      float4 a0 = *(const float4*)&As[k][ty * 8];
      float4 a1 = *(const float4*)&As[k][ty * 8 + 4];
      float4 b0 = *(const float4*)&Bs[k][tx * 4];
      float4 b1 = *(const float4*)&Bs[k][64 + tx * 4];
      float a[8] = {a0.x, a0.y, a0.z, a0.w, a1.x, a1.y, a1.z, a1.w};
      float b[8] = {b0.x, b0.y, b0.z, b0.w, b1.x, b1.y, b1.z, b1.w};
#pragma unroll
      for (int i = 0; i < 8; ++i)
#pragma unroll
        for (int j = 0; j < 8; ++j) acc[i][j] = fmaf(a[i], b[j], acc[i][j]);
    }
    __syncthreads();
  }

#pragma unroll
  for (int i = 0; i < 8; ++i) {
    long row = m0 + ty * 8 + i;
    float4 lo = make_float4(acc[i][0], acc[i][1], acc[i][2], acc[i][3]);
    float4 hi = make_float4(acc[i][4], acc[i][5], acc[i][6], acc[i][7]);
    *(float4*)(C + row * BN + tx * 4) = lo;
    *(float4*)(C + row * BN + 64 + tx * 4) = hi;
  }
}

// ---------------------------------------------------------------------------
// H1[b] = relu(An[b] @ Y[b] + b1)   (per-batch, thread = one of 128 cols)
// ---------------------------------------------------------------------------
__global__ __launch_bounds__(128) void k_prop1(const float* __restrict__ An,
                                               const float* __restrict__ Y,
                                               const float* __restrict__ b1,
                                               float* __restrict__ H1) {
  const int b = blockIdx.x;
  const int f = threadIdx.x;
  const float* Yb = Y + (long)b * NN * FF + f;
  float y[NN];
#pragma unroll
  for (int m = 0; m < NN; ++m) y[m] = Yb[m * FF];
  const float* Ab = An + (long)b * NN * NN;  // uniform addresses -> scalar loads
  const float bias = b1[f];
  float* Hb = H1 + (long)b * NN * FF + f;
#pragma unroll 1
  for (int i = 0; i < NN; ++i) {
    float acc = bias;
#pragma unroll
    for (int m = 0; m < NN; ++m) acc = fmaf(Ab[i * NN + m], y[m], acc);
    Hb[i * FF] = fmaxf(acc, 0.f);
  }
}

// ---------------------------------------------------------------------------
// h2 = relu(An@T + b2); x = relu(h2@Wlin + blin); out = x@Wconv^T + bconv
// ---------------------------------------------------------------------------
__global__ __launch_bounds__(128) void k_final(const float* __restrict__ An,
                                               const float* __restrict__ T,
                                               const float* __restrict__ b2,
                                               const float* __restrict__ Wlin,
                                               const float* __restrict__ blin,
                                               const float* __restrict__ Wconv,
                                               const float* __restrict__ bconv,
                                               float* __restrict__ out) {
  __shared__ float partial[2][NN];
  __shared__ float xs[NN];
  const int b = blockIdx.x;
  const int f = threadIdx.x;
  const int wave = f >> 6;
  const int lane = f & 63;
  const float* Tb = T + (long)b * NN * FF + f;
  float t[NN];
#pragma unroll
  for (int m = 0; m < NN; ++m) t[m] = Tb[m * FF];
  const float* Ab = An + (long)b * NN * NN;
  const float bias = b2[f];
  const float wl = Wlin[f];
#pragma unroll 1
  for (int i = 0; i < NN; ++i) {
    float acc = bias;
#pragma unroll
    for (int m = 0; m < NN; ++m) acc = fmaf(Ab[i * NN + m], t[m], acc);
    float c = fmaxf(acc, 0.f) * wl;  // contribution to x[i]
#pragma unroll
    for (int off = 32; off > 0; off >>= 1) c += __shfl_down(c, off, 64);
    if (lane == 0) partial[wave][i] = c;
  }
  __syncthreads();
  if (f < NN) {
    float x = partial[0][f] + partial[1][f] + blin[0];
    xs[f] = fmaxf(x, 0.f);
  }
  __syncthreads();
  if (f < CC) {
    float o = bconv[f];
#pragma unroll
    for (int i = 0; i < NN; ++i) o = fmaf(xs[i], Wconv[f * NN + i], o);
    out[(long)b * CC + f] = o;
  }
}

// ---------------------------------------------------------------------------
extern "C" void kernel_launch(void* const* d_in, const int* in_sizes, int n_in,
                              void* d_out, int out_size, void* d_ws, size_t ws_size,
                              hipStream_t stream) {
  const float* real  = (const float*)d_in[0];
  // d_in[1] = imag : UNUSED by the reference
  const float* graph = (const float*)d_in[2];
  const float* W1    = (const float*)d_in[3];
  const float* b1    = (const float*)d_in[4];
  const float* W2    = (const float*)d_in[5];
  const float* b2    = (const float*)d_in[6];
  const float* Wlin  = (const float*)d_in[7];
  const float* blin  = (const float*)d_in[8];
  const float* Wconv = (const float*)d_in[9];
  const float* bconv = (const float*)d_in[10];
  float* out = (float*)d_out;

  // workspace layout (floats): An[4096*900] | Y[122880*128] | H1[122880*128]
  float* An = (float*)d_ws;
  float* Y  = An + (long)B_SZ * NN * NN;
  float* H1 = Y + (long)B_SZ * NN * FF;
  float* T  = Y;  // Y is fully consumed by k_prop1 before k_gemm<FF> writes T

  const int M = B_SZ * NN;  // 122880, divisible by 128

  k_norm_adj<<<B_SZ, 128, 0, stream>>>(graph, An);
  k_gemm<INC><<<M / 128, 256, 0, stream>>>(real, W1, Y);
  k_prop1<<<B_SZ, 128, 0, stream>>>(An, Y, b1, H1);
  k_gemm<FF><<<M / 128, 256, 0, stream>>>(H1, W2, T);
  k_final<<<B_SZ, 128, 0, stream>>>(An, T, b2, Wlin, blin, Wconv, bconv, out);
}

// Round 2
// 631.950 us; speedup vs baseline: 1.1997x; 1.1997x over previous
//
#include <hip/hip_runtime.h>
#include <cstdint>

// Problem constants
#define B_SZ 4096
#define NN   30    // nodes
#define INC  512   // in channels
#define FF   128   // hidden
#define CC   9     // out channels

typedef short short8 __attribute__((ext_vector_type(8)));
typedef float f32x4 __attribute__((ext_vector_type(4)));
typedef unsigned short us4 __attribute__((ext_vector_type(4)));

// Split fp32 into bf16 hi + bf16 lo (truncation; residual error ~2^-16 rel)
__device__ inline void split_bf16(float x, unsigned short& hi, unsigned short& lo) {
  uint32_t bits = __float_as_uint(x);
  hi = (unsigned short)(bits >> 16);
  float hif = __uint_as_float(((uint32_t)hi) << 16);
  float r = x - hif;
  lo = (unsigned short)(__float_as_uint(r) >> 16);
}

// ---------------------------------------------------------------------------
// Normalized adjacency: An[b] = D^-1/2 (A + I) D^-1/2 where A = (mean_bands != 0)
// ---------------------------------------------------------------------------
__global__ __launch_bounds__(128) void k_norm_adj(const float* __restrict__ graph,
                                                  float* __restrict__ An) {
  __shared__ float Ah[NN * NN];
  __shared__ float dinv[NN];
  const int b = blockIdx.x;
  const float* g = graph + (long)b * 5 * NN * NN;
  for (int e = threadIdx.x; e < NN * NN; e += 128) {
    float s = g[e] + g[e + 900] + g[e + 1800] + g[e + 2700] + g[e + 3600];
    float mean = s * 0.2f;
    int i = e / NN;
    int j = e - i * NN;
    Ah[e] = (mean != 0.0f || i == j) ? 1.0f : 0.0f;
  }
  __syncthreads();
  if (threadIdx.x < NN) {
    float d = 0.f;
#pragma unroll
    for (int j = 0; j < NN; ++j) d += Ah[threadIdx.x * NN + j];
    dinv[threadIdx.x] = (d > 0.f) ? (1.0f / sqrtf(d)) : 0.0f;
  }
  __syncthreads();
  float* ob = An + (long)b * NN * NN;
  for (int e = threadIdx.x; e < NN * NN; e += 128) {
    int i = e / NN;
    int j = e - i * NN;
    ob[e] = Ah[e] * dinv[i] * dinv[j];
  }
}

// ---------------------------------------------------------------------------
// Pre-split + transpose weights: W [K x 128] fp32 -> Wth/Wtl [128 x K] bf16
// ---------------------------------------------------------------------------
__global__ __launch_bounds__(256) void k_prep_w(const float* __restrict__ W,
                                                unsigned short* __restrict__ Wth,
                                                unsigned short* __restrict__ Wtl,
                                                int K) {
  int idx = blockIdx.x * 256 + threadIdx.x;
  if (idx >= K * FF) return;
  int k = idx >> 7;    // row in W
  int n = idx & 127;   // col in W
  unsigned short h, l;
  split_bf16(W[idx], h, l);
  Wth[n * K + k] = h;
  Wtl[n * K + k] = l;
}

// ---------------------------------------------------------------------------
// Split-bf16 MFMA GEMM: C[M x 128] = A[M x K] * B[K x 128]
// A fp32 row-major (converted inline); B pre-split planes Bth/Btl [128][K].
// BM=BN=128, BK=32, 256 threads = 4 waves in 2x2, each wave 64x64 (4x4 tiles
// of 16x16x32). 3 MFMAs per tile: hi*hi + lo*hi + hi*lo.
// ---------------------------------------------------------------------------
template <int K>
__global__ __launch_bounds__(256) void k_gemm_mfma(const float* __restrict__ A,
                                                   const unsigned short* __restrict__ Bth,
                                                   const unsigned short* __restrict__ Btl,
                                                   float* __restrict__ C) {
  constexpr int BK = 32;
  constexpr int LDT = 48;  // shorts; 96B row stride keeps 16B alignment for b128
  __shared__ unsigned short Ash[128 * LDT];
  __shared__ unsigned short Asl[128 * LDT];
  __shared__ unsigned short Bsh[128 * LDT];
  __shared__ unsigned short Bsl[128 * LDT];

  const int tid = threadIdx.x;
  const int wave = tid >> 6;
  const int lane = tid & 63;
  const int wrow = (wave >> 1) * 64;
  const int wcol = (wave & 1) * 64;
  const int fr = lane & 15;   // row (A) / col (B) within a 16-tile
  const int fq = lane >> 4;   // k-quad: k base = fq*8
  const long m0 = (long)blockIdx.x * 128;

  f32x4 acc[4][4];
#pragma unroll
  for (int i = 0; i < 4; ++i)
#pragma unroll
    for (int j = 0; j < 4; ++j) acc[i][j] = (f32x4){0.f, 0.f, 0.f, 0.f};

  for (int k0 = 0; k0 < K; k0 += BK) {
    // ---- stage A tile (128 x 32 fp32 -> hi/lo bf16) ----
#pragma unroll
    for (int it = 0; it < 4; ++it) {
      int f = tid + it * 256;      // 1024 float4 chunks
      int row = f >> 3;            // 0..127
      int kq = f & 7;              // 0..7, 4 floats each
      float4 v = *(const float4*)(A + (m0 + row) * (long)K + k0 + kq * 4);
      us4 h, l;
      split_bf16(v.x, ((unsigned short*)&h)[0], ((unsigned short*)&l)[0]);
      split_bf16(v.y, ((unsigned short*)&h)[1], ((unsigned short*)&l)[1]);
      split_bf16(v.z, ((unsigned short*)&h)[2], ((unsigned short*)&l)[2]);
      split_bf16(v.w, ((unsigned short*)&h)[3], ((unsigned short*)&l)[3]);
      *(us4*)(Ash + row * LDT + kq * 4) = h;
      *(us4*)(Asl + row * LDT + kq * 4) = l;
    }
    // ---- stage B tile (pre-split bf16 planes, [n][k] layout) ----
#pragma unroll
    for (int it = 0; it < 4; ++it) {
      int f = tid + it * 256;
      int n = f >> 3;
      int kq = f & 7;
      us4 vh = *(const us4*)(Bth + (long)n * K + k0 + kq * 4);
      us4 vl = *(const us4*)(Btl + (long)n * K + k0 + kq * 4);
      *(us4*)(Bsh + n * LDT + kq * 4) = vh;
      *(us4*)(Bsl + n * LDT + kq * 4) = vl;
    }
    __syncthreads();

    // ---- fragments + MFMA ----
    short8 bh[4], bl[4];
#pragma unroll
    for (int ct = 0; ct < 4; ++ct) {
      int n = wcol + ct * 16 + fr;
      bh[ct] = *(const short8*)(Bsh + n * LDT + fq * 8);
      bl[ct] = *(const short8*)(Bsl + n * LDT + fq * 8);
    }
#pragma unroll
    for (int rt = 0; rt < 4; ++rt) {
      int m = wrow + rt * 16 + fr;
      short8 ah = *(const short8*)(Ash + m * LDT + fq * 8);
      short8 al = *(const short8*)(Asl + m * LDT + fq * 8);
#pragma unroll
      for (int ct = 0; ct < 4; ++ct) {
        acc[rt][ct] = __builtin_amdgcn_mfma_f32_16x16x32_bf16(ah, bh[ct], acc[rt][ct], 0, 0, 0);
        acc[rt][ct] = __builtin_amdgcn_mfma_f32_16x16x32_bf16(al, bh[ct], acc[rt][ct], 0, 0, 0);
        acc[rt][ct] = __builtin_amdgcn_mfma_f32_16x16x32_bf16(ah, bl[ct], acc[rt][ct], 0, 0, 0);
      }
    }
    __syncthreads();
  }

  // ---- epilogue: C/D layout col=lane&15, row=(lane>>4)*4+reg ----
#pragma unroll
  for (int rt = 0; rt < 4; ++rt) {
#pragma unroll
    for (int ct = 0; ct < 4; ++ct) {
      int col = wcol + ct * 16 + fr;
#pragma unroll
      for (int r = 0; r < 4; ++r) {
        long row = m0 + wrow + rt * 16 + fq * 4 + r;
        C[row * FF + col] = acc[rt][ct][r];
      }
    }
  }
}

// ---------------------------------------------------------------------------
// H1[b] = relu(An[b] @ Y[b] + b1)   (per-batch, thread = one of 128 cols)
// ---------------------------------------------------------------------------
__global__ __launch_bounds__(128) void k_prop1(const float* __restrict__ An,
                                               const float* __restrict__ Y,
                                               const float* __restrict__ b1,
                                               float* __restrict__ H1) {
  const int b = blockIdx.x;
  const int f = threadIdx.x;
  const float* Yb = Y + (long)b * NN * FF + f;
  float y[NN];
#pragma unroll
  for (int m = 0; m < NN; ++m) y[m] = Yb[m * FF];
  const float* Ab = An + (long)b * NN * NN;  // uniform addresses -> scalar loads
  const float bias = b1[f];
  float* Hb = H1 + (long)b * NN * FF + f;
#pragma unroll 1
  for (int i = 0; i < NN; ++i) {
    float acc = bias;
#pragma unroll
    for (int m = 0; m < NN; ++m) acc = fmaf(Ab[i * NN + m], y[m], acc);
    Hb[i * FF] = fmaxf(acc, 0.f);
  }
}

// ---------------------------------------------------------------------------
// h2 = relu(An@T + b2); x = relu(h2@Wlin + blin); out = x@Wconv^T + bconv
// ---------------------------------------------------------------------------
__global__ __launch_bounds__(128) void k_final(const float* __restrict__ An,
                                               const float* __restrict__ T,
                                               const float* __restrict__ b2,
                                               const float* __restrict__ Wlin,
                                               const float* __restrict__ blin,
                                               const float* __restrict__ Wconv,
                                               const float* __restrict__ bconv,
                                               float* __restrict__ out) {
  __shared__ float partial[2][NN];
  __shared__ float xs[NN];
  const int b = blockIdx.x;
  const int f = threadIdx.x;
  const int wave = f >> 6;
  const int lane = f & 63;
  const float* Tb = T + (long)b * NN * FF + f;
  float t[NN];
#pragma unroll
  for (int m = 0; m < NN; ++m) t[m] = Tb[m * FF];
  const float* Ab = An + (long)b * NN * NN;
  const float bias = b2[f];
  const float wl = Wlin[f];
#pragma unroll 1
  for (int i = 0; i < NN; ++i) {
    float acc = bias;
#pragma unroll
    for (int m = 0; m < NN; ++m) acc = fmaf(Ab[i * NN + m], t[m], acc);
    float c = fmaxf(acc, 0.f) * wl;  // contribution to x[i]
#pragma unroll
    for (int off = 32; off > 0; off >>= 1) c += __shfl_down(c, off, 64);
    if (lane == 0) partial[wave][i] = c;
  }
  __syncthreads();
  if (f < NN) {
    float x = partial[0][f] + partial[1][f] + blin[0];
    xs[f] = fmaxf(x, 0.f);
  }
  __syncthreads();
  if (f < CC) {
    float o = bconv[f];
#pragma unroll
    for (int i = 0; i < NN; ++i) o = fmaf(xs[i], Wconv[f * NN + i], o);
    out[(long)b * CC + f] = o;
  }
}

// ---------------------------------------------------------------------------
extern "C" void kernel_launch(void* const* d_in, const int* in_sizes, int n_in,
                              void* d_out, int out_size, void* d_ws, size_t ws_size,
                              hipStream_t stream) {
  const float* real  = (const float*)d_in[0];
  // d_in[1] = imag : UNUSED by the reference
  const float* graph = (const float*)d_in[2];
  const float* W1    = (const float*)d_in[3];
  const float* b1    = (const float*)d_in[4];
  const float* W2    = (const float*)d_in[5];
  const float* b2    = (const float*)d_in[6];
  const float* Wlin  = (const float*)d_in[7];
  const float* blin  = (const float*)d_in[8];
  const float* Wconv = (const float*)d_in[9];
  const float* bconv = (const float*)d_in[10];
  float* out = (float*)d_out;

  // ws layout (floats): An[4096*900] | Y[122880*128] | H1[122880*128] | W planes
  float* An = (float*)d_ws;
  float* Y  = An + (long)B_SZ * NN * NN;
  float* H1 = Y + (long)B_SZ * NN * FF;
  unsigned short* W1th = (unsigned short*)(H1 + (long)B_SZ * NN * FF);
  unsigned short* W1tl = W1th + INC * FF;
  unsigned short* W2th = W1tl + INC * FF;
  unsigned short* W2tl = W2th + FF * FF;
  float* T = Y;  // Y fully consumed by k_prop1 before gemm2 writes T

  const int M = B_SZ * NN;  // 122880, divisible by 128

  k_norm_adj<<<B_SZ, 128, 0, stream>>>(graph, An);
  k_prep_w<<<(INC * FF + 255) / 256, 256, 0, stream>>>(W1, W1th, W1tl, INC);
  k_prep_w<<<(FF * FF + 255) / 256, 256, 0, stream>>>(W2, W2th, W2tl, FF);
  k_gemm_mfma<INC><<<M / 128, 256, 0, stream>>>(real, W1th, W1tl, Y);
  k_prop1<<<B_SZ, 128, 0, stream>>>(An, Y, b1, H1);
  k_gemm_mfma<FF><<<M / 128, 256, 0, stream>>>(H1, W2th, W2tl, T);
  k_final<<<B_SZ, 128, 0, stream>>>(An, T, b2, Wlin, blin, Wconv, bconv, out);
}